// Round 1
// baseline (274.271 us; speedup 1.0000x reference)
//
#include <hip/hip_runtime.h>
#include <cstdint>
#include <cstddef>

typedef unsigned short u16;
typedef unsigned int   u32;

typedef __bf16 bf16x8 __attribute__((ext_vector_type(8)));
typedef float  f32x4  __attribute__((ext_vector_type(4)));

#define NROWS 4096
#define INF   512
#define OUTF  512
#define EMB   64
#define MHID  128
#define DB    9
#define KDIM  (INF * DB)   /* 4608 */
#define MN    (NROWS * OUTF)   /* 2097152 */

__device__ __forceinline__ u16 f2bf(float f) {
    union { float f; u32 ui; } v; v.f = f;
    u32 u = v.ui;
    u += 0x7fffu + ((u >> 16) & 1u);   // RTNE
    return (u16)(u >> 16);
}
__device__ __forceinline__ float gridv(int t) { return (float)(t - 3) * 0.4f - 1.0f; }

// ---------------- kernel 1: meff — one wave per output ----------------
__global__ __launch_bounds__(256) void meff_kernel(
    const float* __restrict__ w1_0, const float* __restrict__ b1_0,
    const float* __restrict__ w2_0, const float* __restrict__ b2_0,
    const float* __restrict__ w1_1, const float* __restrict__ b1_1,
    const float* __restrict__ w2_1, const float* __restrict__ b2_1,
    float* __restrict__ Mc)
{
    int tid  = threadIdx.x;
    int lane = tid & 63;
    int wid  = blockIdx.x * 4 + (tid >> 6);
    if (wid >= 1170) return;
    int layer = wid / 585;
    int o     = wid % 585;
    const float* w1 = layer ? w1_1 : w1_0;
    const float* b1 = layer ? b1_1 : b1_0;
    const float* w2 = layer ? w2_1 : w2_0;
    const float* b2 = layer ? b2_1 : b2_0;

    float p;
    int d;
    if (o < 576) {
        int j = o / 9; d = o % 9;
        p = w1[lane * EMB + j]        * w2[d * MHID + lane]
          + w1[(lane + 64) * EMB + j] * w2[d * MHID + lane + 64];
    } else {
        d = o - 576;
        p = b1[lane] * w2[d * MHID + lane] + b1[lane + 64] * w2[d * MHID + lane + 64];
    }
#pragma unroll
    for (int off = 32; off >= 1; off >>= 1)
        p += __shfl_xor(p, off, 64);
    if (lane == 0) {
        if (o >= 576) p += b2[d];
        Mc[layer * 1024 + o] = p;
    }
}

// ---------------- kernel 2: genw v6 — LDS-free, per-thread-row register loads --
// R5 counters: genw latency-bound (MfmaUtil 0, VALUBusy 10%, HBM 16%,
// Occupancy 17%) — the 65-KB tile caps residency at 2 blocks/CU and every
// wave drains on the same stage vmcnt+barrier. The tile only converted
// coalesced loads into per-thread-row reads, but a row IS 16 contiguous
// float4s: load them straight to registers (all 16 in flight, L1/MSHR
// merges the 8 requests per 128-B line). LDS drops to the 4.6-KB out-stage,
// both input barriers go away, occupancy becomes VGPR-limited (~5 waves/EU).
__global__ __launch_bounds__(256, 4) void genw_kernel(
    const float* __restrict__ emb0, const float* __restrict__ emb1,
    const float* __restrict__ Mc,
    u16* __restrict__ Bw0, u16* __restrict__ Bw1)
{
    __shared__ __align__(16) u16 ob[256 * 9];   // 4608 B out-stage only
    int layer = blockIdx.y;
    const float* emb = layer ? emb1 : emb0;
    u16* Bw = layer ? Bw1 : Bw0;
    const float* mc = Mc + layer * 1024;

    int tid = threadIdx.x;
    size_t row = (size_t)blockIdx.x * 256 + tid;

    // issue all 16 row loads up front; compiler interleaves vmcnt waits with FMA
    const float4* g4 = (const float4*)(emb + row * EMB);
    float4 v[16];
#pragma unroll
    for (int j = 0; j < 16; ++j) v[j] = g4[j];

    float acc[9];
#pragma unroll
    for (int d = 0; d < 9; ++d) acc[d] = mc[576 + d];    // c[d] (uniform)

#pragma unroll
    for (int jj = 0; jj < 16; ++jj) {
#pragma unroll
        for (int d = 0; d < 9; ++d)
            acc[d] += v[jj].x * mc[(jj * 4 + 0) * 9 + d]   // uniform -> SGPR
                    + v[jj].y * mc[(jj * 4 + 1) * 9 + d]
                    + v[jj].z * mc[(jj * 4 + 2) * 9 + d]
                    + v[jj].w * mc[(jj * 4 + 3) * 9 + d];
    }

#pragma unroll
    for (int d = 0; d < 9; ++d) ob[tid * 9 + d] = f2bf(acc[d]);
    __syncthreads();

    const uint4* src = (const uint4*)ob;                     // 288 uint4
    uint4* dst = (uint4*)(Bw + (size_t)blockIdx.x * 256 * 9);
    for (int s = tid; s < 288; s += 256) dst[s] = src[s];
}

// ---------------- kernel 3: phi — div-free spline + silu ----------------
__global__ __launch_bounds__(256) void phi_kernel(const float* __restrict__ xin,
                                                  const float* __restrict__ part,
                                                  int S,
                                                  u16* __restrict__ phi)
{
    __shared__ __align__(16) u16 lbuf[256 * 9];   // 4608 B
    int tid = threadIdx.x;
    int idx = blockIdx.x * 256 + tid;

    float xv;
    if (part) {
        xv = 0.f;
        for (int z = 0; z < S; ++z) xv += part[(size_t)z * MN + idx];
    } else {
        xv = xin[idx];
    }

    float b[11];
#pragma unroll
    for (int t = 0; t < 11; ++t)
        b[t] = (xv >= gridv(t) && xv < gridv(t + 1)) ? 1.0f : 0.0f;
#pragma unroll
    for (int k = 1; k <= 3; ++k) {
#pragma unroll
        for (int t = 0; t + k < 11; ++t) {
            float rdp = 1.0f / ((gridv(t + k) - gridv(t)) + 1e-8f);
            float rdn = 1.0f / ((gridv(t + k + 1) - gridv(t + 1)) + 1e-8f);
            b[t] = (xv - gridv(t)) * rdp * b[t] + (gridv(t + k + 1) - xv) * rdn * b[t + 1];
        }
    }
    float sil = xv / (1.0f + expf(-xv));

#pragma unroll
    for (int d = 0; d < 8; ++d) lbuf[tid * 9 + d] = f2bf(b[d]);
    lbuf[tid * 9 + 8] = f2bf(sil);
    __syncthreads();

    const uint4* src = (const uint4*)lbuf;        // 288 uint4
    uint4* dst = (uint4*)(phi + (size_t)blockIdx.x * 256 * 9);
    for (int s = tid; s < 288; s += 256) dst[s] = src[s];
}

// ---------------- kernel 4: split-K GEMM  Cpart[z] = A[:,kz] * B[:,kz]^T ----------
#define GLOAD16(gp, lp) __builtin_amdgcn_global_load_lds(                         \
    (const __attribute__((address_space(1))) u32*)(gp),                           \
    (__attribute__((address_space(3))) u32*)(lp), 16, 0, 0)

__global__ __launch_bounds__(256, 4) void gemm_kernel(const __bf16* __restrict__ A,
                                                      const __bf16* __restrict__ B,
                                                      float* __restrict__ Cpart,
                                                      int N, int K, int ksz)
{
    __shared__ __align__(16) __bf16 As[128 * 64];
    __shared__ __align__(16) __bf16 Bs[128 * 64];

    int tid  = threadIdx.x;
    int lane = tid & 63;
    int wv   = tid >> 6;
    int wm   = wv >> 1, wn = wv & 1;
    int brow = blockIdx.x * 128;
    int bcol = blockIdx.y * 128;
    int z    = blockIdx.z;
    int kbeg = z * ksz, kend = kbeg + ksz;

    f32x4 acc[4][4];
#pragma unroll
    for (int r = 0; r < 4; ++r)
#pragma unroll
        for (int c = 0; c < 4; ++c)
#pragma unroll
            for (int g = 0; g < 4; ++g) acc[r][c][g] = 0.0f;

    int quad = lane >> 4;
    int l16  = lane & 15;

    for (int k0 = kbeg; k0 < kend; k0 += 64) {
#pragma unroll
        for (int q = 0; q < 4; ++q) {
            int chunk = q * 256 + wv * 64 + lane;
            int row   = chunk >> 3;
            int slot  = chunk & 7;
            int col   = ((slot ^ (row & 7)) << 3);   // XOR swizzle (0 conflicts, R2)
            const __bf16* ga = A + (size_t)(brow + row) * K + (k0 + col);
            const __bf16* gb = B + (size_t)(bcol + row) * K + (k0 + col);
            GLOAD16(ga, &As[(q * 256 + wv * 64) * 8]);
            GLOAD16(gb, &Bs[(q * 256 + wv * 64) * 8]);
        }
        __syncthreads();

#pragma unroll
        for (int ks = 0; ks < 2; ++ks) {
            bf16x8 af[4], bfr[4];
#pragma unroll
            for (int r = 0; r < 4; ++r) {
                int arow = wm * 64 + r * 16 + l16;
                af[r] = *(const bf16x8*)&As[arow * 64 + (((ks * 4 + quad) ^ (arow & 7)) << 3)];
                int brw = wn * 64 + r * 16 + l16;
                bfr[r] = *(const bf16x8*)&Bs[brw * 64 + (((ks * 4 + quad) ^ (brw & 7)) << 3)];
            }
#pragma unroll
            for (int r = 0; r < 4; ++r)
#pragma unroll
                for (int c = 0; c < 4; ++c)
                    acc[r][c] = __builtin_amdgcn_mfma_f32_16x16x32_bf16(af[r], bfr[c], acc[r][c], 0, 0, 0);
        }
        __syncthreads();
    }

    float* Cz = Cpart + (size_t)z * MN;
#pragma unroll
    for (int r = 0; r < 4; ++r)
#pragma unroll
        for (int c = 0; c < 4; ++c)
#pragma unroll
            for (int g = 0; g < 4; ++g) {
                int grow = brow + wm * 64 + r * 16 + quad * 4 + g;
                int gcol = bcol + wn * 64 + c * 16 + l16;
                Cz[(size_t)grow * N + gcol] = acc[r][c][g];
            }
}

// ---------------- kernel 5: final reduce (float4) ----------------
__global__ __launch_bounds__(256) void reduce_kernel(const float* __restrict__ part,
                                                     int S, float* __restrict__ out)
{
    int i = blockIdx.x * 256 + threadIdx.x;
    const float4* p4 = (const float4*)part;
    float4 s = p4[i];
    for (int z = 1; z < S; ++z) {
        float4 v = p4[(size_t)z * (MN / 4) + i];
        s.x += v.x; s.y += v.y; s.z += v.z; s.w += v.w;
    }
    ((float4*)out)[i] = s;
}

// ---------------- launch ----------------
extern "C" void kernel_launch(void* const* d_in, const int* in_sizes, int n_in,
                              void* d_out, int out_size, void* d_ws, size_t ws_size,
                              hipStream_t stream)
{
    const float* x    = (const float*)d_in[0];
    const float* emb0 = (const float*)d_in[1];
    const float* w1_0 = (const float*)d_in[2];
    const float* b1_0 = (const float*)d_in[3];
    const float* w2_0 = (const float*)d_in[4];
    const float* b2_0 = (const float*)d_in[5];
    const float* emb1 = (const float*)d_in[6];
    const float* w1_1 = (const float*)d_in[7];
    const float* b1_1 = (const float*)d_in[8];
    const float* w2_1 = (const float*)d_in[9];
    const float* b2_1 = (const float*)d_in[10];

    char* ws = (char*)d_ws;
    const size_t PHI_OFF  = 0;                       // 37,748,736
    const size_t BW0_OFF  = 37748736;                //  4,718,592
    const size_t BW1_OFF  = BW0_OFF + 4718592;
    const size_t MC_OFF   = BW1_OFF + 4718592;       //  8,192
    const size_t PART_OFF = MC_OFF + 8192;

    // split-K: S=4 (R3 vs R4 A/B: S=8 cost ~+19 us in partial traffic)
    int S = 1;
    const size_t SLAB = 8388608ull;
    if      (ws_size >= PART_OFF + 4 * SLAB) S = 4;
    else if (ws_size >= PART_OFF + 2 * SLAB) S = 2;
    int ksz = KDIM / S;

    u16*   phi  = (u16*)(ws + PHI_OFF);
    u16*   Bw0  = (u16*)(ws + BW0_OFF);
    u16*   Bw1  = (u16*)(ws + BW1_OFF);
    float* Mc   = (float*)(ws + MC_OFF);
    float* part = (float*)(ws + PART_OFF);

    meff_kernel<<<293, 256, 0, stream>>>(w1_0, b1_0, w2_0, b2_0,
                                         w1_1, b1_1, w2_1, b2_1, Mc);
    genw_kernel<<<dim3(1024, 2), 256, 0, stream>>>(emb0, emb1, Mc, Bw0, Bw1);

    phi_kernel<<<8192, 256, 0, stream>>>(x, nullptr, 0, phi);
    gemm_kernel<<<dim3(32, 4, S), 256, 0, stream>>>((const __bf16*)phi, (const __bf16*)Bw0,
                                                    part, OUTF, KDIM, ksz);
    phi_kernel<<<8192, 256, 0, stream>>>(nullptr, part, S, phi);
    gemm_kernel<<<dim3(32, 4, S), 256, 0, stream>>>((const __bf16*)phi, (const __bf16*)Bw1,
                                                    part, OUTF, KDIM, ksz);
    reduce_kernel<<<2048, 256, 0, stream>>>(part, S, (float*)d_out);
}

// Round 3
// 273.237 us; speedup vs baseline: 1.0038x; 1.0038x over previous
//
#include <hip/hip_runtime.h>
#include <cstdint>
#include <cstddef>

typedef unsigned short u16;
typedef unsigned int   u32;

typedef __bf16 bf16x8 __attribute__((ext_vector_type(8)));
typedef float  f32x4  __attribute__((ext_vector_type(4)));

#define NROWS 4096
#define INF   512
#define OUTF  512
#define EMB   64
#define MHID  128
#define DB    9
#define KDIM  (INF * DB)   /* 4608 */
#define MN    (NROWS * OUTF)   /* 2097152 */

__device__ __forceinline__ u16 f2bf(float f) {
    union { float f; u32 ui; } v; v.f = f;
    u32 u = v.ui;
    u += 0x7fffu + ((u >> 16) & 1u);   // RTNE
    return (u16)(u >> 16);
}
__device__ __forceinline__ float gridv(int t) { return (float)(t - 3) * 0.4f - 1.0f; }

// ---------------- kernel 1: meff — one wave per output ----------------
__global__ __launch_bounds__(256) void meff_kernel(
    const float* __restrict__ w1_0, const float* __restrict__ b1_0,
    const float* __restrict__ w2_0, const float* __restrict__ b2_0,
    const float* __restrict__ w1_1, const float* __restrict__ b1_1,
    const float* __restrict__ w2_1, const float* __restrict__ b2_1,
    float* __restrict__ Mc)
{
    int tid  = threadIdx.x;
    int lane = tid & 63;
    int wid  = blockIdx.x * 4 + (tid >> 6);
    if (wid >= 1170) return;
    int layer = wid / 585;
    int o     = wid % 585;
    const float* w1 = layer ? w1_1 : w1_0;
    const float* b1 = layer ? b1_1 : b1_0;
    const float* w2 = layer ? w2_1 : w2_0;
    const float* b2 = layer ? b2_1 : b2_0;

    float p;
    int d;
    if (o < 576) {
        int j = o / 9; d = o % 9;
        p = w1[lane * EMB + j]        * w2[d * MHID + lane]
          + w1[(lane + 64) * EMB + j] * w2[d * MHID + lane + 64];
    } else {
        d = o - 576;
        p = b1[lane] * w2[d * MHID + lane] + b1[lane + 64] * w2[d * MHID + lane + 64];
    }
#pragma unroll
    for (int off = 32; off >= 1; off >>= 1)
        p += __shfl_xor(p, off, 64);
    if (lane == 0) {
        if (o >= 576) p += b2[d];
        Mc[layer * 1024 + o] = p;
    }
}

// ---------------- kernel 2: genw v7 — lane-split rows, per-inst coalescing --
// R6 counters: per-thread-row register loads over-fetched 1.75x (each wave
// inst touches 64 distinct lines; L1/MSHR can't hold 128 lines x 11 waves
// until the 8-deep same-line reuse completes). Fix: consume each line WITHIN
// one instruction. Lane l owns col-group (l&15) of row (l>>4): one float4
// per lane per iter = 1 KB contiguous per wave inst, zero cross-inst reuse
// needed. M moves from SGPR to 36 per-lane VGPRs (4 cols x 9), row-sum via
// 4-step shfl_xor butterfly over the 16-lane group. Prefetch depth 2.
// (R2 resubmit: previous run was an infra failure, no counters returned.)
__global__ __launch_bounds__(256) void genw_kernel(
    const float* __restrict__ emb0, const float* __restrict__ emb1,
    const float* __restrict__ Mc,
    u16* __restrict__ Bw0, u16* __restrict__ Bw1)
{
    __shared__ __align__(16) u16 ob[256 * 9];   // 4608 B out-stage only
    int layer = blockIdx.y;
    const float* emb = layer ? emb1 : emb0;
    u16* Bw = layer ? Bw1 : Bw0;
    const float* mc = Mc + layer * 1024;

    int tid  = threadIdx.x;
    int lane = tid & 63;
    int w    = tid >> 6;
    int cg   = lane & 15;      // col-group: cols cg*4 .. cg*4+3
    int rg   = lane >> 4;      // row within the 4-row group

    // per-lane M block: M[e*9+d] = mc[(cg*4+e)*9 + d]  (36 floats, 144B-aligned)
    float M[36];
    {
        const float4* m4 = (const float4*)(mc + cg * 36);
#pragma unroll
        for (int q = 0; q < 9; ++q) {
            float4 t = m4[q];
            M[q * 4 + 0] = t.x; M[q * 4 + 1] = t.y;
            M[q * 4 + 2] = t.z; M[q * 4 + 3] = t.w;
        }
    }
    float c9[9];
#pragma unroll
    for (int d = 0; d < 9; ++d) c9[d] = mc[576 + d];   // uniform

    size_t base_row = (size_t)blockIdx.x * 256 + (size_t)w * 64;
    const float4* g4 = (const float4*)(emb + base_row * EMB);

    // iter i covers rows base_row + i*4 + rg; lane reads float4 #(i*64+lane)
    float4 vc = g4[lane];
#pragma unroll
    for (int i = 0; i < 16; ++i) {
        float4 vn;
        if (i < 15) vn = g4[(i + 1) * 64 + lane];

        float p[9];
#pragma unroll
        for (int d = 0; d < 9; ++d)
            p[d] = vc.x * M[d] + vc.y * M[9 + d] + vc.z * M[18 + d] + vc.w * M[27 + d];

#pragma unroll
        for (int s = 1; s <= 8; s <<= 1)
#pragma unroll
            for (int d = 0; d < 9; ++d)
                p[d] += __shfl_xor(p[d], s, 64);

        if (cg == 0) {
            int r = w * 64 + i * 4 + rg;
#pragma unroll
            for (int d = 0; d < 9; ++d) ob[r * 9 + d] = f2bf(p[d] + c9[d]);
        }
        vc = vn;
    }

    __syncthreads();
    const uint4* src = (const uint4*)ob;                     // 288 uint4
    uint4* dst = (uint4*)(Bw + (size_t)blockIdx.x * 256 * 9);
    for (int s = tid; s < 288; s += 256) dst[s] = src[s];
}

// ---------------- kernel 3: phi — div-free spline + silu ----------------
__global__ __launch_bounds__(256) void phi_kernel(const float* __restrict__ xin,
                                                  const float* __restrict__ part,
                                                  int S,
                                                  u16* __restrict__ phi)
{
    __shared__ __align__(16) u16 lbuf[256 * 9];   // 4608 B
    int tid = threadIdx.x;
    int idx = blockIdx.x * 256 + tid;

    float xv;
    if (part) {
        xv = 0.f;
        for (int z = 0; z < S; ++z) xv += part[(size_t)z * MN + idx];
    } else {
        xv = xin[idx];
    }

    float b[11];
#pragma unroll
    for (int t = 0; t < 11; ++t)
        b[t] = (xv >= gridv(t) && xv < gridv(t + 1)) ? 1.0f : 0.0f;
#pragma unroll
    for (int k = 1; k <= 3; ++k) {
#pragma unroll
        for (int t = 0; t + k < 11; ++t) {
            float rdp = 1.0f / ((gridv(t + k) - gridv(t)) + 1e-8f);
            float rdn = 1.0f / ((gridv(t + k + 1) - gridv(t + 1)) + 1e-8f);
            b[t] = (xv - gridv(t)) * rdp * b[t] + (gridv(t + k + 1) - xv) * rdn * b[t + 1];
        }
    }
    float sil = xv / (1.0f + expf(-xv));

#pragma unroll
    for (int d = 0; d < 8; ++d) lbuf[tid * 9 + d] = f2bf(b[d]);
    lbuf[tid * 9 + 8] = f2bf(sil);
    __syncthreads();

    const uint4* src = (const uint4*)lbuf;        // 288 uint4
    uint4* dst = (uint4*)(phi + (size_t)blockIdx.x * 256 * 9);
    for (int s = tid; s < 288; s += 256) dst[s] = src[s];
}

// ---------------- kernel 4: split-K GEMM  Cpart[z] = A[:,kz] * B[:,kz]^T ----------
#define GLOAD16(gp, lp) __builtin_amdgcn_global_load_lds(                         \
    (const __attribute__((address_space(1))) u32*)(gp),                           \
    (__attribute__((address_space(3))) u32*)(lp), 16, 0, 0)

__global__ __launch_bounds__(256, 4) void gemm_kernel(const __bf16* __restrict__ A,
                                                      const __bf16* __restrict__ B,
                                                      float* __restrict__ Cpart,
                                                      int N, int K, int ksz)
{
    __shared__ __align__(16) __bf16 As[128 * 64];
    __shared__ __align__(16) __bf16 Bs[128 * 64];

    int tid  = threadIdx.x;
    int lane = tid & 63;
    int wv   = tid >> 6;
    int wm   = wv >> 1, wn = wv & 1;
    int brow = blockIdx.x * 128;
    int bcol = blockIdx.y * 128;
    int z    = blockIdx.z;
    int kbeg = z * ksz, kend = kbeg + ksz;

    f32x4 acc[4][4];
#pragma unroll
    for (int r = 0; r < 4; ++r)
#pragma unroll
        for (int c = 0; c < 4; ++c)
#pragma unroll
            for (int g = 0; g < 4; ++g) acc[r][c][g] = 0.0f;

    int quad = lane >> 4;
    int l16  = lane & 15;

    for (int k0 = kbeg; k0 < kend; k0 += 64) {
#pragma unroll
        for (int q = 0; q < 4; ++q) {
            int chunk = q * 256 + wv * 64 + lane;
            int row   = chunk >> 3;
            int slot  = chunk & 7;
            int col   = ((slot ^ (row & 7)) << 3);   // XOR swizzle (0 conflicts, R2)
            const __bf16* ga = A + (size_t)(brow + row) * K + (k0 + col);
            const __bf16* gb = B + (size_t)(bcol + row) * K + (k0 + col);
            GLOAD16(ga, &As[(q * 256 + wv * 64) * 8]);
            GLOAD16(gb, &Bs[(q * 256 + wv * 64) * 8]);
        }
        __syncthreads();

#pragma unroll
        for (int ks = 0; ks < 2; ++ks) {
            bf16x8 af[4], bfr[4];
#pragma unroll
            for (int r = 0; r < 4; ++r) {
                int arow = wm * 64 + r * 16 + l16;
                af[r] = *(const bf16x8*)&As[arow * 64 + (((ks * 4 + quad) ^ (arow & 7)) << 3)];
                int brw = wn * 64 + r * 16 + l16;
                bfr[r] = *(const bf16x8*)&Bs[brw * 64 + (((ks * 4 + quad) ^ (brw & 7)) << 3)];
            }
#pragma unroll
            for (int r = 0; r < 4; ++r)
#pragma unroll
                for (int c = 0; c < 4; ++c)
                    acc[r][c] = __builtin_amdgcn_mfma_f32_16x16x32_bf16(af[r], bfr[c], acc[r][c], 0, 0, 0);
        }
        __syncthreads();
    }

    float* Cz = Cpart + (size_t)z * MN;
#pragma unroll
    for (int r = 0; r < 4; ++r)
#pragma unroll
        for (int c = 0; c < 4; ++c)
#pragma unroll
            for (int g = 0; g < 4; ++g) {
                int grow = brow + wm * 64 + r * 16 + quad * 4 + g;
                int gcol = bcol + wn * 64 + c * 16 + l16;
                Cz[(size_t)grow * N + gcol] = acc[r][c][g];
            }
}

// ---------------- kernel 5: final reduce (float4) ----------------
__global__ __launch_bounds__(256) void reduce_kernel(const float* __restrict__ part,
                                                     int S, float* __restrict__ out)
{
    int i = blockIdx.x * 256 + threadIdx.x;
    const float4* p4 = (const float4*)part;
    float4 s = p4[i];
    for (int z = 1; z < S; ++z) {
        float4 v = p4[(size_t)z * (MN / 4) + i];
        s.x += v.x; s.y += v.y; s.z += v.z; s.w += v.w;
    }
    ((float4*)out)[i] = s;
}

// ---------------- launch ----------------
extern "C" void kernel_launch(void* const* d_in, const int* in_sizes, int n_in,
                              void* d_out, int out_size, void* d_ws, size_t ws_size,
                              hipStream_t stream)
{
    const float* x    = (const float*)d_in[0];
    const float* emb0 = (const float*)d_in[1];
    const float* w1_0 = (const float*)d_in[2];
    const float* b1_0 = (const float*)d_in[3];
    const float* w2_0 = (const float*)d_in[4];
    const float* b2_0 = (const float*)d_in[5];
    const float* emb1 = (const float*)d_in[6];
    const float* w1_1 = (const float*)d_in[7];
    const float* b1_1 = (const float*)d_in[8];
    const float* w2_1 = (const float*)d_in[9];
    const float* b2_1 = (const float*)d_in[10];

    char* ws = (char*)d_ws;
    const size_t PHI_OFF  = 0;                       // 37,748,736
    const size_t BW0_OFF  = 37748736;                //  4,718,592
    const size_t BW1_OFF  = BW0_OFF + 4718592;
    const size_t MC_OFF   = BW1_OFF + 4718592;       //  8,192
    const size_t PART_OFF = MC_OFF + 8192;

    // split-K: S=4 (R3 vs R4 A/B: S=8 cost ~+19 us in partial traffic)
    int S = 1;
    const size_t SLAB = 8388608ull;
    if      (ws_size >= PART_OFF + 4 * SLAB) S = 4;
    else if (ws_size >= PART_OFF + 2 * SLAB) S = 2;
    int ksz = KDIM / S;

    u16*   phi  = (u16*)(ws + PHI_OFF);
    u16*   Bw0  = (u16*)(ws + BW0_OFF);
    u16*   Bw1  = (u16*)(ws + BW1_OFF);
    float* Mc   = (float*)(ws + MC_OFF);
    float* part = (float*)(ws + PART_OFF);

    meff_kernel<<<293, 256, 0, stream>>>(w1_0, b1_0, w2_0, b2_0,
                                         w1_1, b1_1, w2_1, b2_1, Mc);
    genw_kernel<<<dim3(1024, 2), 256, 0, stream>>>(emb0, emb1, Mc, Bw0, Bw1);

    phi_kernel<<<8192, 256, 0, stream>>>(x, nullptr, 0, phi);
    gemm_kernel<<<dim3(32, 4, S), 256, 0, stream>>>((const __bf16*)phi, (const __bf16*)Bw0,
                                                    part, OUTF, KDIM, ksz);
    phi_kernel<<<8192, 256, 0, stream>>>(nullptr, part, S, phi);
    gemm_kernel<<<dim3(32, 4, S), 256, 0, stream>>>((const __bf16*)phi, (const __bf16*)Bw1,
                                                    part, OUTF, KDIM, ksz);
    reduce_kernel<<<2048, 256, 0, stream>>>(part, S, (float*)d_out);
}

// Round 4
// 260.917 us; speedup vs baseline: 1.0512x; 1.0472x over previous
//
#include <hip/hip_runtime.h>
#include <cstdint>
#include <cstddef>

typedef unsigned short u16;
typedef unsigned int   u32;

typedef __bf16 bf16x8 __attribute__((ext_vector_type(8)));
typedef float  f32x4  __attribute__((ext_vector_type(4)));

#define NROWS 4096
#define INF   512
#define OUTF  512
#define EMB   64
#define MHID  128
#define DB    9
#define KDIM  (INF * DB)   /* 4608 */
#define MN    (NROWS * OUTF)   /* 2097152 */

__device__ __forceinline__ u16 f2bf(float f) {
    union { float f; u32 ui; } v; v.f = f;
    u32 u = v.ui;
    u += 0x7fffu + ((u >> 16) & 1u);   // RTNE
    return (u16)(u >> 16);
}
__device__ __forceinline__ float gridv(int t) { return (float)(t - 3) * 0.4f - 1.0f; }

// ---------------- kernel 1: meff — one wave per output ----------------
__global__ __launch_bounds__(256) void meff_kernel(
    const float* __restrict__ w1_0, const float* __restrict__ b1_0,
    const float* __restrict__ w2_0, const float* __restrict__ b2_0,
    const float* __restrict__ w1_1, const float* __restrict__ b1_1,
    const float* __restrict__ w2_1, const float* __restrict__ b2_1,
    float* __restrict__ Mc)
{
    int tid  = threadIdx.x;
    int lane = tid & 63;
    int wid  = blockIdx.x * 4 + (tid >> 6);
    if (wid >= 1170) return;
    int layer = wid / 585;
    int o     = wid % 585;
    const float* w1 = layer ? w1_1 : w1_0;
    const float* b1 = layer ? b1_1 : b1_0;
    const float* w2 = layer ? w2_1 : w2_0;
    const float* b2 = layer ? b2_1 : b2_0;

    float p;
    int d;
    if (o < 576) {
        int j = o / 9; d = o % 9;
        p = w1[lane * EMB + j]        * w2[d * MHID + lane]
          + w1[(lane + 64) * EMB + j] * w2[d * MHID + lane + 64];
    } else {
        d = o - 576;
        p = b1[lane] * w2[d * MHID + lane] + b1[lane + 64] * w2[d * MHID + lane + 64];
    }
#pragma unroll
    for (int off = 32; off >= 1; off >>= 1)
        p += __shfl_xor(p, off, 64);
    if (lane == 0) {
        if (o >= 576) p += b2[d];
        Mc[layer * 1024 + o] = p;
    }
}

// ---------------- kernel 2: genw v8 — b128 LDS transpose, no shfl ----------
// R7 post-mortem: v7's 576 shfl/wave saturated the per-CU DS pipe
// (8192 waves x 576 / 256 CU x ~6cyc ~= 46 us — the observed floor; VALUBusy
// 22%, HBM 14%, occupancy 47% all idle). v8 kills the reduction: row-per-
// thread with SGPR M (readfirstlane'd half-select -> compile-time mc[]
// indices -> s_load), emb transposed through a 32-KB float4-swizzled tile
// (8 ds_write_b128 + 8 ds_read_b128 per thread, 2-way max conflict). Halves
// combine via stride-9 (odd -> conflict-free) 4.6-KB LDS buffer.
__global__ __launch_bounds__(256) void genw_kernel(
    const float* __restrict__ emb0, const float* __restrict__ emb1,
    const float* __restrict__ Mc,
    u16* __restrict__ Bw0, u16* __restrict__ Bw1)
{
    __shared__ __align__(16) float4 tile[128 * 16];   // 32768 B, c4-XOR swizzle
    __shared__ __align__(16) float  pbuf[128 * 9];    //  4608 B partials (stride 9, odd)
    __shared__ __align__(16) u16    ob[128 * 9];      //  2304 B out-stage
    int layer = blockIdx.y;
    const float* emb = layer ? emb1 : emb0;
    u16* Bw = layer ? Bw1 : Bw0;
    const float* mc = Mc + layer * 1024;

    int tid = threadIdx.x;
    size_t rowbase = (size_t)blockIdx.x * 128;

    // stage 128 rows x 16 float4, coalesced, b128 LDS writes
    const float4* g4 = (const float4*)(emb + rowbase * EMB);
#pragma unroll
    for (int q = 0; q < 8; ++q) {
        int f = q * 256 + tid;               // 0..2047
        float4 v = g4[f];
        int row = f >> 4, c4 = f & 15;
        tile[row * 16 + (c4 ^ (row & 15))] = v;
    }
    __syncthreads();

    int r  = tid & 127;                      // owned row
    int hi = tid >> 7;                       // 0: cols 0-31, 1: cols 32-63 (wave-uniform)
    int cb = hi * 8;                         // float4 base in tile
    // SGPR base so mc[] offsets are compile-time constants -> s_load
    const float* mcp = mc + __builtin_amdgcn_readfirstlane(hi) * 32 * 9;

    float acc[9];
#pragma unroll
    for (int d = 0; d < 9; ++d) acc[d] = hi ? 0.0f : mc[576 + d];

#pragma unroll
    for (int jj = 0; jj < 8; ++jj) {
        float4 v = tile[r * 16 + ((cb + jj) ^ (r & 15))];
#pragma unroll
        for (int d = 0; d < 9; ++d)
            acc[d] += v.x * mcp[(jj * 4 + 0) * 9 + d]
                    + v.y * mcp[(jj * 4 + 1) * 9 + d]
                    + v.z * mcp[(jj * 4 + 2) * 9 + d]
                    + v.w * mcp[(jj * 4 + 3) * 9 + d];
    }

    if (hi) {
#pragma unroll
        for (int d = 0; d < 9; ++d) pbuf[r * 9 + d] = acc[d];
    }
    __syncthreads();
    if (!hi) {
#pragma unroll
        for (int d = 0; d < 9; ++d) ob[r * 9 + d] = f2bf(acc[d] + pbuf[r * 9 + d]);
    }
    __syncthreads();

    const uint4* src = (const uint4*)ob;                   // 144 uint4
    uint4* dst = (uint4*)(Bw + rowbase * 9);               // 2304 B/block, aligned
    if (tid < 144) dst[tid] = src[tid];
}

// ---------------- kernel 3: phi — div-free spline + silu ----------------
__global__ __launch_bounds__(256) void phi_kernel(const float* __restrict__ xin,
                                                  const float* __restrict__ part,
                                                  int S,
                                                  u16* __restrict__ phi)
{
    __shared__ __align__(16) u16 lbuf[256 * 9];   // 4608 B
    int tid = threadIdx.x;
    int idx = blockIdx.x * 256 + tid;

    float xv;
    if (part) {
        xv = 0.f;
        for (int z = 0; z < S; ++z) xv += part[(size_t)z * MN + idx];
    } else {
        xv = xin[idx];
    }

    float b[11];
#pragma unroll
    for (int t = 0; t < 11; ++t)
        b[t] = (xv >= gridv(t) && xv < gridv(t + 1)) ? 1.0f : 0.0f;
#pragma unroll
    for (int k = 1; k <= 3; ++k) {
#pragma unroll
        for (int t = 0; t + k < 11; ++t) {
            float rdp = 1.0f / ((gridv(t + k) - gridv(t)) + 1e-8f);
            float rdn = 1.0f / ((gridv(t + k + 1) - gridv(t + 1)) + 1e-8f);
            b[t] = (xv - gridv(t)) * rdp * b[t] + (gridv(t + k + 1) - xv) * rdn * b[t + 1];
        }
    }
    float sil = xv / (1.0f + expf(-xv));

#pragma unroll
    for (int d = 0; d < 8; ++d) lbuf[tid * 9 + d] = f2bf(b[d]);
    lbuf[tid * 9 + 8] = f2bf(sil);
    __syncthreads();

    const uint4* src = (const uint4*)lbuf;        // 288 uint4
    uint4* dst = (uint4*)(phi + (size_t)blockIdx.x * 256 * 9);
    for (int s = tid; s < 288; s += 256) dst[s] = src[s];
}

// ---------------- kernel 4: split-K GEMM  Cpart[z] = A[:,kz] * B[:,kz]^T ----------
#define GLOAD16(gp, lp) __builtin_amdgcn_global_load_lds(                         \
    (const __attribute__((address_space(1))) u32*)(gp),                           \
    (__attribute__((address_space(3))) u32*)(lp), 16, 0, 0)

__global__ __launch_bounds__(256, 4) void gemm_kernel(const __bf16* __restrict__ A,
                                                      const __bf16* __restrict__ B,
                                                      float* __restrict__ Cpart,
                                                      int N, int K, int ksz)
{
    __shared__ __align__(16) __bf16 As[128 * 64];
    __shared__ __align__(16) __bf16 Bs[128 * 64];

    int tid  = threadIdx.x;
    int lane = tid & 63;
    int wv   = tid >> 6;
    int wm   = wv >> 1, wn = wv & 1;
    int brow = blockIdx.x * 128;
    int bcol = blockIdx.y * 128;
    int z    = blockIdx.z;
    int kbeg = z * ksz, kend = kbeg + ksz;

    f32x4 acc[4][4];
#pragma unroll
    for (int r = 0; r < 4; ++r)
#pragma unroll
        for (int c = 0; c < 4; ++c)
#pragma unroll
            for (int g = 0; g < 4; ++g) acc[r][c][g] = 0.0f;

    int quad = lane >> 4;
    int l16  = lane & 15;

    for (int k0 = kbeg; k0 < kend; k0 += 64) {
#pragma unroll
        for (int q = 0; q < 4; ++q) {
            int chunk = q * 256 + wv * 64 + lane;
            int row   = chunk >> 3;
            int slot  = chunk & 7;
            int col   = ((slot ^ (row & 7)) << 3);   // XOR swizzle (0 conflicts, R2)
            const __bf16* ga = A + (size_t)(brow + row) * K + (k0 + col);
            const __bf16* gb = B + (size_t)(bcol + row) * K + (k0 + col);
            GLOAD16(ga, &As[(q * 256 + wv * 64) * 8]);
            GLOAD16(gb, &Bs[(q * 256 + wv * 64) * 8]);
        }
        __syncthreads();

#pragma unroll
        for (int ks = 0; ks < 2; ++ks) {
            bf16x8 af[4], bfr[4];
#pragma unroll
            for (int r = 0; r < 4; ++r) {
                int arow = wm * 64 + r * 16 + l16;
                af[r] = *(const bf16x8*)&As[arow * 64 + (((ks * 4 + quad) ^ (arow & 7)) << 3)];
                int brw = wn * 64 + r * 16 + l16;
                bfr[r] = *(const bf16x8*)&Bs[brw * 64 + (((ks * 4 + quad) ^ (brw & 7)) << 3)];
            }
#pragma unroll
            for (int r = 0; r < 4; ++r)
#pragma unroll
                for (int c = 0; c < 4; ++c)
                    acc[r][c] = __builtin_amdgcn_mfma_f32_16x16x32_bf16(af[r], bfr[c], acc[r][c], 0, 0, 0);
        }
        __syncthreads();
    }

    float* Cz = Cpart + (size_t)z * MN;
#pragma unroll
    for (int r = 0; r < 4; ++r)
#pragma unroll
        for (int c = 0; c < 4; ++c)
#pragma unroll
            for (int g = 0; g < 4; ++g) {
                int grow = brow + wm * 64 + r * 16 + quad * 4 + g;
                int gcol = bcol + wn * 64 + c * 16 + l16;
                Cz[(size_t)grow * N + gcol] = acc[r][c][g];
            }
}

// ---------------- kernel 5: final reduce (float4) ----------------
__global__ __launch_bounds__(256) void reduce_kernel(const float* __restrict__ part,
                                                     int S, float* __restrict__ out)
{
    int i = blockIdx.x * 256 + threadIdx.x;
    const float4* p4 = (const float4*)part;
    float4 s = p4[i];
    for (int z = 1; z < S; ++z) {
        float4 v = p4[(size_t)z * (MN / 4) + i];
        s.x += v.x; s.y += v.y; s.z += v.z; s.w += v.w;
    }
    ((float4*)out)[i] = s;
}

// ---------------- launch ----------------
extern "C" void kernel_launch(void* const* d_in, const int* in_sizes, int n_in,
                              void* d_out, int out_size, void* d_ws, size_t ws_size,
                              hipStream_t stream)
{
    const float* x    = (const float*)d_in[0];
    const float* emb0 = (const float*)d_in[1];
    const float* w1_0 = (const float*)d_in[2];
    const float* b1_0 = (const float*)d_in[3];
    const float* w2_0 = (const float*)d_in[4];
    const float* b2_0 = (const float*)d_in[5];
    const float* emb1 = (const float*)d_in[6];
    const float* w1_1 = (const float*)d_in[7];
    const float* b1_1 = (const float*)d_in[8];
    const float* w2_1 = (const float*)d_in[9];
    const float* b2_1 = (const float*)d_in[10];

    char* ws = (char*)d_ws;
    const size_t PHI_OFF  = 0;                       // 37,748,736
    const size_t BW0_OFF  = 37748736;                //  4,718,592
    const size_t BW1_OFF  = BW0_OFF + 4718592;
    const size_t MC_OFF   = BW1_OFF + 4718592;       //  8,192
    const size_t PART_OFF = MC_OFF + 8192;

    // split-K: S=4 (R3 vs R4 A/B: S=8 cost ~+19 us in partial traffic)
    int S = 1;
    const size_t SLAB = 8388608ull;
    if      (ws_size >= PART_OFF + 4 * SLAB) S = 4;
    else if (ws_size >= PART_OFF + 2 * SLAB) S = 2;
    int ksz = KDIM / S;

    u16*   phi  = (u16*)(ws + PHI_OFF);
    u16*   Bw0  = (u16*)(ws + BW0_OFF);
    u16*   Bw1  = (u16*)(ws + BW1_OFF);
    float* Mc   = (float*)(ws + MC_OFF);
    float* part = (float*)(ws + PART_OFF);

    meff_kernel<<<293, 256, 0, stream>>>(w1_0, b1_0, w2_0, b2_0,
                                         w1_1, b1_1, w2_1, b2_1, Mc);
    genw_kernel<<<dim3(2048, 2), 256, 0, stream>>>(emb0, emb1, Mc, Bw0, Bw1);

    phi_kernel<<<8192, 256, 0, stream>>>(x, nullptr, 0, phi);
    gemm_kernel<<<dim3(32, 4, S), 256, 0, stream>>>((const __bf16*)phi, (const __bf16*)Bw0,
                                                    part, OUTF, KDIM, ksz);
    phi_kernel<<<8192, 256, 0, stream>>>(nullptr, part, S, phi);
    gemm_kernel<<<dim3(32, 4, S), 256, 0, stream>>>((const __bf16*)phi, (const __bf16*)Bw1,
                                                    part, OUTF, KDIM, ksz);
    reduce_kernel<<<2048, 256, 0, stream>>>(part, S, (float*)d_out);
}